// Round 2
// baseline (495.271 us; speedup 1.0000x reference)
//
#include <hip/hip_runtime.h>
#include <hip/hip_bf16.h>

#define NN 100000
#define EE 640000
#define DD 128
#define RR 8
#define K8 (NN * RR)      // 800000 (rel,dst) pair keys, key = r*NN + dst
#define NSB2 196          // ceil(K8/4096)
#define NB 1563           // ceil(NN/64) gemm_agg blocks

typedef __attribute__((ext_vector_type(8))) short short8;
typedef __attribute__((ext_vector_type(4))) float floatx4;
typedef __attribute__((ext_vector_type(4))) unsigned int uint4v;

__device__ __forceinline__ unsigned short f2bf(float f) {
  unsigned int u = __float_as_uint(f);
  u += 0x7FFFu + ((u >> 16) & 1u);   // RNE
  return (unsigned short)(u >> 16);
}
__device__ __forceinline__ unsigned int pk2bf(float a, float b) {
  __hip_bfloat162 h = __float22bfloat162_rn(make_float2(a, b));
  unsigned int u;
  __builtin_memcpy(&u, &h, 4);
  return u;                          // low16 = a, high16 = b
}
__device__ __forceinline__ float bflo(unsigned int u) { return __uint_as_float(u << 16); }
__device__ __forceinline__ float bfhi(unsigned int u) { return __uint_as_float(u & 0xFFFF0000u); }

// ---------------------------------------------------------------------------
// x (fp32 [NN][128]) -> Xb (bf16 std rows as uints: uint j = cols 2j|2j+1<<16)
// ---------------------------------------------------------------------------
__global__ __launch_bounds__(256) void xb_prep(
    const float* __restrict__ x, unsigned int* __restrict__ xb)
{
  int g = blockIdx.x * 256 + threadIdx.x;
  int v = g >> 4, seg = g & 15;
  const float4* s4 = (const float4*)(x + (size_t)v * 128 + seg * 8);
  float4 a = s4[0], b = s4[1];
  uint4v o;
  o[0] = pk2bf(a.x, a.y); o[1] = pk2bf(a.z, a.w);
  o[2] = pk2bf(b.x, b.y); o[3] = pk2bf(b.z, b.w);
  *(uint4v*)(xb + (size_t)v * 64 + seg * 4) = o;
}

// ---------------------------------------------------------------------------
// Weights: wt[set][r][n][k] = bf16(W[kk][n]); r=8 is root.
// Set 1 (layer 2) permutes k to match layer-1's packed epilogue layout:
// h1 element e holds column 32*(e>>5... ) -> kk = 32*((e>>1)>>4) + ((e>>1)&15) + 16*(e&1).
// ---------------------------------------------------------------------------
__global__ __launch_bounds__(256) void w_prep_all(
    const float* __restrict__ rel1, const float* __restrict__ root1,
    const float* __restrict__ rel2, const float* __restrict__ root2,
    unsigned short* __restrict__ wt)
{
  int id = blockIdx.x * 256 + threadIdx.x;       // [0, 2*9*16384)
  int set = id >= 147456;
  int rem = id - set * 147456;
  int r = rem >> 14, n = (rem >> 7) & 127, k = rem & 127;
  int kk = k;
  if (set) {
    int u = k >> 1, w2 = u >> 4, m2 = u & 15;
    kk = w2 * 32 + m2 + ((k & 1) << 4);
  }
  const float* rel = set ? rel2 : rel1;
  const float* root = set ? root2 : root1;
  float v = (r < RR) ? rel[((size_t)r * DD + kk) * DD + n] : root[(size_t)kk * DD + n];
  wt[id] = f2bf(v);
}

// ---------------------------------------------------------------------------
// One atomic per edge; its return value is the edge's rank in its (r,dst)
// segment so no later atomic is needed anywhere.
// ---------------------------------------------------------------------------
__global__ __launch_bounds__(256) void count_all(
    const int* __restrict__ ei, const int* __restrict__ et,
    int* __restrict__ cnt, int* __restrict__ erank)
{
  int e = blockIdx.x * 256 + threadIdx.x;
  int dst = ei[EE + e], r = et[e];
  erank[e] = atomicAdd(&cnt[r * NN + dst], 1);
}

// ---------------------------------------------------------------------------
// 3-phase exclusive scan over cnt[K8] -> rowptr[K8+1].
// ---------------------------------------------------------------------------
__global__ __launch_bounds__(256) void scan_a(
    const int4* __restrict__ c4, int n4, int* __restrict__ bsum)
{
  int t = threadIdx.x;
  int s = 0;
#pragma unroll
  for (int i = 0; i < 4; ++i) {
    int idx = blockIdx.x * 1024 + i * 256 + t;
    if (idx < n4) { int4 v = c4[idx]; s += v.x + v.y + v.z + v.w; }
  }
  __shared__ int wsum[4];
  for (int d = 32; d; d >>= 1) s += __shfl_xor(s, d, 64);
  if ((t & 63) == 0) wsum[t >> 6] = s;
  __syncthreads();
  if (t == 0) bsum[blockIdx.x] = wsum[0] + wsum[1] + wsum[2] + wsum[3];
}

__global__ void scan_b(const int* __restrict__ bsum, int nsb,
                       int* __restrict__ bbase)
{
  int lane = threadIdx.x;                         // 64 threads
  int v[4]; int s = 0;
#pragma unroll
  for (int i = 0; i < 4; ++i) {
    int idx = lane * 4 + i;
    v[i] = (idx < nsb) ? bsum[idx] : 0; s += v[i];
  }
  int inc = s;
  for (int d = 1; d < 64; d <<= 1) {
    int o = __shfl_up(inc, d, 64);
    if (lane >= d) inc += o;
  }
  int running = inc - s;
#pragma unroll
  for (int i = 0; i < 4; ++i) {
    int idx = lane * 4 + i;
    if (idx < nsb) { bbase[idx] = running; running += v[i]; }
  }
}

__global__ __launch_bounds__(256) void scan_c(
    const int* __restrict__ cnt, const int* __restrict__ bbase, int n,
    int* __restrict__ out0)
{
  int t = threadIdx.x;
  int base = blockIdx.x * 4096 + t * 16;
  int v[16]; int s = 0;
#pragma unroll
  for (int i = 0; i < 16; ++i) {
    int idx = base + i;
    v[i] = (idx < n) ? cnt[idx] : 0;
    s += v[i];
  }
  int lane = t & 63, wid = t >> 6;
  int inc = s;
  for (int d = 1; d < 64; d <<= 1) {
    int o = __shfl_up(inc, d, 64);
    if (lane >= d) inc += o;
  }
  __shared__ int wsum[4];
  if (lane == 63) wsum[wid] = inc;
  __syncthreads();
  int wb = 0;
  for (int w = 0; w < wid; ++w) wb += wsum[w];
  int running = bbase[blockIdx.x] + wb + (inc - s);
#pragma unroll
  for (int i = 0; i < 16; ++i) {
    int idx = base + i;
    if (idx < n) { out0[idx] = running; running += v[i]; }
  }
  if (blockIdx.x == 0 && t == 0) out0[n] = EE;
}

// ---------------------------------------------------------------------------
// Place edge srcs into (r,dst)-major CSR, no atomics.
// ---------------------------------------------------------------------------
__global__ __launch_bounds__(256) void place(
    const int* __restrict__ ei, const int* __restrict__ et,
    const int* __restrict__ rowptr, const int* __restrict__ erank,
    int* __restrict__ recs)
{
  int e = blockIdx.x * 256 + threadIdx.x;
  int src = ei[e], dst = ei[EE + e], r = et[e];
  recs[rowptr[r * NN + dst] + erank[e]] = src;
}

// ---------------------------------------------------------------------------
// Fused aggregate-then-GEMM. Block owns 64 dst rows. Per relation r:
//   8-lane groups compute segment means of Xb rows (f32 reg accum, 2-deep
//   pipelined gather) -> bf16 A-tile in LDS (rotated layout) -> MFMA with
//   W_r, accumulating across all 9 rounds (8 rel + root). Epilogue adds
//   bias, ReLU, writes packed bf16 (layer 1) or fp32 (layer 2) directly.
// ---------------------------------------------------------------------------
#define MFMA_ROUND()                                                          \
  {                                                                           \
    __syncthreads();                                                          \
    _Pragma("unroll")                                                         \
    for (int ks = 0; ks < 4; ++ks) {                                          \
      short8 a[4];                                                            \
      _Pragma("unroll")                                                       \
      for (int mi = 0; mi < 4; ++mi)                                          \
        a[mi] = *(const short8*)&As[(mi * 16 + mr) * 128 +                    \
                                    ((ks * 32 + quad * 8 + mr * 8) & 127)];   \
      _Pragma("unroll")                                                       \
      for (int mi = 0; mi < 4; ++mi) {                                        \
        acc[mi][0] = __builtin_amdgcn_mfma_f32_16x16x32_bf16(                 \
            a[mi], b0[ks], acc[mi][0], 0, 0, 0);                              \
        acc[mi][1] = __builtin_amdgcn_mfma_f32_16x16x32_bf16(                 \
            a[mi], b1[ks], acc[mi][1], 0, 0, 0);                              \
      }                                                                       \
    }                                                                         \
    __syncthreads();                                                          \
  }

__global__ __launch_bounds__(256, 3) void gemm_agg(
    const unsigned int* __restrict__ Xb,     // [NN][64] packed bf16 rows
    const unsigned short* __restrict__ Wt,   // [9][128][128] bf16 [r][n][k]
    const int* __restrict__ rowptr,          // [K8+1]
    const int* __restrict__ recs,            // [EE] src per slot
    const float* __restrict__ bias,          // [128]
    void* __restrict__ outp, int out_bf16)
{
  const int v0 = blockIdx.x * 64;
  __shared__ unsigned short As[64 * 128];    // 16 KB
  __shared__ int Rp[8 * 65];                 // rowptr slice for this block

  const int tid = threadIdx.x;
  const int wave = tid >> 6, lane = tid & 63;
  const int quad = lane >> 4, mr = lane & 15;
  const int g = lane >> 3, li = lane & 7;
  const uint4v* Xb4 = (const uint4v*)Xb;
  unsigned int* Asu = (unsigned int*)As;

  for (int id = tid; id < 520; id += 256) {
    int r = id / 65, j = id - r * 65;
    int k = r * NN + v0 + j;
    Rp[id] = rowptr[min(k, K8)];
  }

  floatx4 acc[4][2];
#pragma unroll
  for (int mi = 0; mi < 4; ++mi) {
    acc[mi][0] = (floatx4){0.f, 0.f, 0.f, 0.f};
    acc[mi][1] = (floatx4){0.f, 0.f, 0.f, 0.f};
  }
  __syncthreads();

#pragma unroll 1
  for (int r = 0; r < 8; ++r) {
    // B fragments for this relation (consumed after the barrier)
    const unsigned short* wr =
        Wt + (size_t)r * 16384 + (size_t)(wave * 32 + mr) * 128 + quad * 8;
    short8 b0[4], b1[4];
#pragma unroll
    for (int ks = 0; ks < 4; ++ks) {
      b0[ks] = *(const short8*)(wr + ks * 32);
      b1[ks] = *(const short8*)(wr + 16 * 128 + ks * 32);
    }

    // ---- segment means: 8-lane group per dst row, 2 passes of 8 rows/wave
#pragma unroll
    for (int half = 0; half < 2; ++half) {
      int d = wave * 16 + half * 8 + g;
      int v = v0 + d;
      int b = Rp[r * 65 + d];
      int e = (v < NN) ? Rp[r * 65 + d + 1] : b;
      int cnt = e - b;
      int recv = (li < cnt) ? recs[b + li] : 0;   // first 8 srcs, lane-parallel
      float f[16];
#pragma unroll
      for (int j = 0; j < 16; ++j) f[j] = 0.f;

      int srcC = __shfl(recv, (g << 3), 64);
      uint4v u0c{}, u1c{};
      if (cnt > 0) {
        const uint4v* xp = Xb4 + (size_t)srcC * 16 + li * 2;
        u0c = xp[0]; u1c = xp[1];
      }
      for (int t = 0; __any(t < cnt); ++t) {
        int tn = t + 1;
        int srcN = __shfl(recv, (g << 3) + (tn & 7), 64);
        bool actN = tn < cnt;
        if (actN && tn >= 8) srcN = recs[b + tn];  // rare long segment
        uint4v u0n{}, u1n{};
        if (actN) {
          const uint4v* xp = Xb4 + (size_t)srcN * 16 + li * 2;
          u0n = xp[0]; u1n = xp[1];
        }
        if (t < cnt) {
          unsigned um[8];
          *(uint4v*)&um[0] = u0c; *(uint4v*)&um[4] = u1c;
#pragma unroll
          for (int m = 0; m < 8; ++m) {
            f[2 * m]     += bflo(um[m]);
            f[2 * m + 1] += bfhi(um[m]);
          }
        }
        u0c = u0n; u1c = u1n;
      }
      float sc = 1.0f / (float)max(cnt, 1);
      int rot = (d & 15) * 4;
      uint4v o0, o1;
#pragma unroll
      for (int m = 0; m < 4; ++m)
        o0[m] = pk2bf(f[2 * m] * sc, f[2 * m + 1] * sc);
#pragma unroll
      for (int m = 0; m < 4; ++m)
        o1[m] = pk2bf(f[8 + 2 * m] * sc, f[9 + 2 * m] * sc);
      *(uint4v*)&Asu[d * 64 + ((li * 8 + rot) & 63)] = o0;
      *(uint4v*)&Asu[d * 64 + ((li * 8 + rot + 4) & 63)] = o1;
    }
    MFMA_ROUND();
  }

  // ---- root round: A-tile = Xb rows v0..v0+63 (sequential) ----
  {
    const unsigned short* wr =
        Wt + (size_t)8 * 16384 + (size_t)(wave * 32 + mr) * 128 + quad * 8;
    short8 b0[4], b1[4];
#pragma unroll
    for (int ks = 0; ks < 4; ++ks) {
      b0[ks] = *(const short8*)(wr + ks * 32);
      b1[ks] = *(const short8*)(wr + 16 * 128 + ks * 32);
    }
    int row = tid >> 2, q = tid & 3;
    int v = v0 + row;
    int src = (v < NN) ? v : 0;
    const uint4v* xs = Xb4 + (size_t)src * 16 + q * 4;
#pragma unroll
    for (int c = 0; c < 4; ++c) {
      uint4v vv = xs[c];
      int pos = (q * 16 + c * 4 + (row & 15) * 4) & 63;
      *(uint4v*)&Asu[row * 64 + pos] = vv;
    }
    MFMA_ROUND();
  }

  // ---- epilogue: bias + ReLU, direct store ----
  float bia0 = bias[wave * 32 + mr], bia1 = bias[wave * 32 + 16 + mr];
#pragma unroll
  for (int mi = 0; mi < 4; ++mi)
#pragma unroll
    for (int rg = 0; rg < 4; ++rg) {
      int row = mi * 16 + quad * 4 + rg;
      int v = v0 + row;
      if (v < NN) {
        float c0 = fmaxf(acc[mi][0][rg] + bia0, 0.f);
        float c1 = fmaxf(acc[mi][1][rg] + bia1, 0.f);
        if (out_bf16) {
          ((unsigned int*)outp)[(size_t)v * 64 + wave * 16 + mr] = pk2bf(c0, c1);
        } else {
          float* o = (float*)outp;
          o[(size_t)v * 128 + wave * 32 + mr] = c0;
          o[(size_t)v * 128 + wave * 32 + 16 + mr] = c1;
        }
      }
    }
}

// ---------------------------------------------------------------------------
extern "C" void kernel_launch(void* const* d_in, const int* in_sizes, int n_in,
                              void* d_out, int out_size, void* d_ws, size_t ws_size,
                              hipStream_t stream) {
  const float* x       = (const float*)d_in[0];
  const int*   ei      = (const int*)d_in[1];
  const int*   et      = (const int*)d_in[2];
  const float* rel_w1  = (const float*)d_in[3];
  const float* root_w1 = (const float*)d_in[4];
  const float* b1      = (const float*)d_in[5];
  const float* rel_w2  = (const float*)d_in[6];
  const float* root_w2 = (const float*)d_in[7];
  const float* b2      = (const float*)d_in[8];

  char* ws = (char*)d_ws;
  size_t off = 0;
  auto alloc = [&](size_t bytes) { char* p = ws + off; off = (off + bytes + 255) & ~(size_t)255; return p; };
  unsigned int*   Xb    = (unsigned int*)alloc((size_t)NN * 64 * 4);         // 25.6 MB
  unsigned int*   h1    = (unsigned int*)alloc((size_t)NN * 64 * 4);         // 25.6 MB (permuted pack)
  unsigned short* Wt    = (unsigned short*)alloc((size_t)2 * 9 * DD * DD * 2);
  int*            cnt   = (int*)alloc((size_t)K8 * 4);                       // 3.2 MB (zeroed)
  int*            rowptr= (int*)alloc((size_t)(K8 + 1) * 4);                 // 3.2 MB
  int*            erank = (int*)alloc((size_t)EE * 4);                       // 2.56 MB
  int*            recs  = (int*)alloc((size_t)EE * 4);                       // 2.56 MB
  int*            bsum  = (int*)alloc((size_t)NSB2 * 4);
  int*            bbase = (int*)alloc((size_t)NSB2 * 4);

  hipMemsetAsync(cnt, 0, (size_t)K8 * 4, stream);

  xb_prep<<<(NN * 16) / 256, 256, 0, stream>>>(x, Xb);
  w_prep_all<<<(2 * 9 * DD * DD) / 256, 256, 0, stream>>>(rel_w1, root_w1, rel_w2, root_w2, Wt);
  count_all<<<EE / 256, 256, 0, stream>>>(ei, et, cnt, erank);

  scan_a<<<NSB2, 256, 0, stream>>>((const int4*)cnt, K8 / 4, bsum);
  scan_b<<<1, 64, 0, stream>>>(bsum, NSB2, bbase);
  scan_c<<<NSB2, 256, 0, stream>>>(cnt, bbase, K8, rowptr);

  place<<<EE / 256, 256, 0, stream>>>(ei, et, rowptr, erank, recs);

  gemm_agg<<<NB, 256, 0, stream>>>(Xb, Wt, rowptr, recs, b1, h1, 1);
  gemm_agg<<<NB, 256, 0, stream>>>(h1, Wt + (size_t)9 * DD * DD, rowptr, recs, b2, d_out, 0);
}